// Round 1
// baseline (634.873 us; speedup 1.0000x reference)
//
#include <hip/hip_runtime.h>
#include <hip/hip_bf16.h>

typedef __bf16 bf16;
typedef __bf16 bf16x8 __attribute__((ext_vector_type(8)));
typedef float f32x4 __attribute__((ext_vector_type(4)));

#define ROWS 64
#define LDST 264  // bf16 elements per LDS row: 256 + 8 pad (528B -> 16B aligned, 2-way bank alias only)

// ---------------- prep: transpose 256x256 fp32 weights -> bf16 [N][K] ----------------
__global__ void transpose_weights(const float* __restrict__ w, bf16* __restrict__ out)
{
    __shared__ float tile[64][65];
    const int m  = blockIdx.z;              // matrix (level) 0..5
    const int k0 = blockIdx.x * 64;
    const int n0 = blockIdx.y * 64;
    const float* src = w + (size_t)m * 65536;
    bf16* dst = out + (size_t)m * 65536;
    const int tx = threadIdx.x & 63, ty = threadIdx.x >> 6;
#pragma unroll
    for (int i = ty; i < 64; i += 4)
        tile[i][tx] = src[(size_t)(k0 + i) * 256 + n0 + tx];
    __syncthreads();
#pragma unroll
    for (int i = ty; i < 64; i += 4)
        dst[(size_t)(n0 + i) * 256 + k0 + tx] = (bf16)tile[tx][i];
}

// ---------------- prep: [6][256][10] -> [6][16][256] bf16, transposed + zero-padded ----------------
__global__ void prep_small(const float* __restrict__ w, bf16* __restrict__ out)
{
    int idx = blockIdx.x * 256 + threadIdx.x;  // 6*16*256 = 24576
    int k = idx & 255;
    int n = (idx >> 8) & 15;
    int l = idx >> 12;
    float v = (n < 10) ? w[((size_t)l * 256 + k) * 10 + n] : 0.0f;
    out[idx] = (bf16)v;
}

// ---------------- main fused head kernel ----------------
// 64x256 tile GEMM: acc[4 m-tiles][2 n-tiles], wave owns cols [wave*32, wave*32+32)
__device__ __forceinline__ void gemm64(const bf16* __restrict__ bufIn,
                                       const bf16* __restrict__ wt,
                                       int wave, int lane, f32x4 acc[4][2])
{
    const int quad = lane >> 4, lx = lane & 15;
    const int ncol0 = wave * 32;
#pragma unroll
    for (int mt = 0; mt < 4; mt++)
#pragma unroll
        for (int nt = 0; nt < 2; nt++)
            acc[mt][nt] = f32x4{0.f, 0.f, 0.f, 0.f};
#pragma unroll
    for (int kk = 0; kk < 8; kk++) {
        const int k0 = kk * 32 + quad * 8;
        bf16x8 a[4], b[2];
#pragma unroll
        for (int mt = 0; mt < 4; mt++)
            a[mt] = *(const bf16x8*)&bufIn[(mt * 16 + lx) * LDST + k0];
#pragma unroll
        for (int nt = 0; nt < 2; nt++)
            b[nt] = *(const bf16x8*)&wt[(ncol0 + nt * 16 + lx) * 256 + k0];
#pragma unroll
        for (int mt = 0; mt < 4; mt++)
#pragma unroll
            for (int nt = 0; nt < 2; nt++)
                acc[mt][nt] = __builtin_amdgcn_mfma_f32_16x16x32_bf16(a[mt], b[nt], acc[mt][nt], 0, 0, 0);
    }
}

// 16x256 @ 256x16 GEMM (final small layers)
__device__ __forceinline__ f32x4 gemm16(const bf16* __restrict__ bufIn,
                                        const bf16* __restrict__ wt,
                                        int mrow0, int lane)
{
    const int quad = lane >> 4, lx = lane & 15;
    f32x4 acc = f32x4{0.f, 0.f, 0.f, 0.f};
#pragma unroll
    for (int kk = 0; kk < 8; kk++) {
        const int k0 = kk * 32 + quad * 8;
        bf16x8 a = *(const bf16x8*)&bufIn[(mrow0 + lx) * LDST + k0];
        bf16x8 b = *(const bf16x8*)&wt[lx * 256 + k0];
        acc = __builtin_amdgcn_mfma_f32_16x16x32_bf16(a, b, acc, 0, 0, 0);
    }
    return acc;
}

__global__ __launch_bounds__(512) void head_kernel(
    const float* __restrict__ hs, const float* __restrict__ init_ref,
    const float* __restrict__ inter_ref,
    const bf16* __restrict__ cw1t, const bf16* __restrict__ cw2t,
    const bf16* __restrict__ rw1t, const bf16* __restrict__ rw2t,
    const bf16* __restrict__ cw3t, const bf16* __restrict__ rw3t,
    const float* __restrict__ cb1, const float* __restrict__ g1, const float* __restrict__ b1,
    const float* __restrict__ cb2, const float* __restrict__ g2, const float* __restrict__ b2,
    const float* __restrict__ cb3,
    const float* __restrict__ rb1, const float* __restrict__ rb2, const float* __restrict__ rb3,
    float* __restrict__ out)
{
    __shared__ bf16 bufH[ROWS * LDST];
    __shared__ bf16 bufA[ROWS * LDST];
    __shared__ bf16 bufB[ROWS * LDST];
    __shared__ float red0[8][ROWS];
    __shared__ float red1[8][ROWS];
    __shared__ float rowMean[ROWS];
    __shared__ float rowRstd[ROWS];

    const int l    = blockIdx.y;
    const int tile = blockIdx.x;
    const int row0 = tile * ROWS;
    const int tid  = threadIdx.x;
    const int wave = tid >> 6;
    const int lane = tid & 63;
    const int quad = lane >> 4;
    const int lx   = lane & 15;

    // ---- stage h tile: hs[l][q][b][:] -> bufH[r][:] bf16, r = b*900 + q ----
    for (int ri = wave; ri < ROWS; ri += 8) {
        const int r = row0 + ri;
        const int b = r / 900;
        const int q = r - b * 900;
        const float4* src = (const float4*)(hs + (((size_t)l * 900 + q) * 32 + b) * 256);
        float4 v = src[lane];
        union { bf16 h[4]; uint2 u; } pk;
        pk.h[0] = (bf16)v.x; pk.h[1] = (bf16)v.y; pk.h[2] = (bf16)v.z; pk.h[3] = (bf16)v.w;
        *(uint2*)&bufH[ri * LDST + lane * 4] = pk.u;
    }
    __syncthreads();

    f32x4 acc[4][2];
    float z[4][2][4];

    // ================= cls layer 1: LN(h@cw1+cb1), relu -> bufA =================
    gemm64(bufH, cw1t + (size_t)l * 65536, wave, lane, acc);
    {
        const float bv0 = cb1[l * 256 + wave * 32 + lx];
        const float bv1 = cb1[l * 256 + wave * 32 + 16 + lx];
        float s[16], ss[16];
#pragma unroll
        for (int mt = 0; mt < 4; mt++)
#pragma unroll
            for (int r = 0; r < 4; r++) {
                float a0 = acc[mt][0][r] + bv0;
                float a1 = acc[mt][1][r] + bv1;
                z[mt][0][r] = a0; z[mt][1][r] = a1;
                s[mt * 4 + r]  = a0 + a1;
                ss[mt * 4 + r] = a0 * a0 + a1 * a1;
            }
#pragma unroll
        for (int off = 1; off < 16; off <<= 1)
#pragma unroll
            for (int i = 0; i < 16; i++) {
                s[i]  += __shfl_xor(s[i], off);
                ss[i] += __shfl_xor(ss[i], off);
            }
        if (lx == 0) {
#pragma unroll
            for (int mt = 0; mt < 4; mt++)
#pragma unroll
                for (int r = 0; r < 4; r++) {
                    int row = mt * 16 + quad * 4 + r;
                    red0[wave][row] = s[mt * 4 + r];
                    red1[wave][row] = ss[mt * 4 + r];
                }
        }
        __syncthreads();
        if (tid < ROWS) {
            float st = 0.f, sst = 0.f;
#pragma unroll
            for (int w = 0; w < 8; w++) { st += red0[w][tid]; sst += red1[w][tid]; }
            float mean = st * (1.f / 256.f);
            float var  = sst * (1.f / 256.f) - mean * mean;
            rowMean[tid] = mean;
            rowRstd[tid] = rsqrtf(var + 1e-5f);
        }
        __syncthreads();
#pragma unroll
        for (int nt = 0; nt < 2; nt++) {
            const int col = wave * 32 + nt * 16 + lx;
            const float gv = g1[l * 256 + col], bbv = b1[l * 256 + col];
#pragma unroll
            for (int mt = 0; mt < 4; mt++)
#pragma unroll
                for (int r = 0; r < 4; r++) {
                    int row = mt * 16 + quad * 4 + r;
                    float v = (z[mt][nt][r] - rowMean[row]) * rowRstd[row] * gv + bbv;
                    bufA[row * LDST + col] = (bf16)fmaxf(v, 0.f);
                }
        }
    }
    __syncthreads();

    // ================= reg layer 1: relu(h@rw1+rb1) -> bufB =================
    gemm64(bufH, rw1t + (size_t)l * 65536, wave, lane, acc);
    {
#pragma unroll
        for (int nt = 0; nt < 2; nt++) {
            const int col = wave * 32 + nt * 16 + lx;
            const float bv = rb1[l * 256 + col];
#pragma unroll
            for (int mt = 0; mt < 4; mt++)
#pragma unroll
                for (int r = 0; r < 4; r++) {
                    int row = mt * 16 + quad * 4 + r;
                    bufB[row * LDST + col] = (bf16)fmaxf(acc[mt][nt][r] + bv, 0.f);
                }
        }
    }
    __syncthreads();

    // ================= cls layer 2: LN(x1@cw2+cb2), relu -> bufH =================
    gemm64(bufA, cw2t + (size_t)l * 65536, wave, lane, acc);
    {
        const float bv0 = cb2[l * 256 + wave * 32 + lx];
        const float bv1 = cb2[l * 256 + wave * 32 + 16 + lx];
        float s[16], ss[16];
#pragma unroll
        for (int mt = 0; mt < 4; mt++)
#pragma unroll
            for (int r = 0; r < 4; r++) {
                float a0 = acc[mt][0][r] + bv0;
                float a1 = acc[mt][1][r] + bv1;
                z[mt][0][r] = a0; z[mt][1][r] = a1;
                s[mt * 4 + r]  = a0 + a1;
                ss[mt * 4 + r] = a0 * a0 + a1 * a1;
            }
#pragma unroll
        for (int off = 1; off < 16; off <<= 1)
#pragma unroll
            for (int i = 0; i < 16; i++) {
                s[i]  += __shfl_xor(s[i], off);
                ss[i] += __shfl_xor(ss[i], off);
            }
        if (lx == 0) {
#pragma unroll
            for (int mt = 0; mt < 4; mt++)
#pragma unroll
                for (int r = 0; r < 4; r++) {
                    int row = mt * 16 + quad * 4 + r;
                    red0[wave][row] = s[mt * 4 + r];
                    red1[wave][row] = ss[mt * 4 + r];
                }
        }
        __syncthreads();
        if (tid < ROWS) {
            float st = 0.f, sst = 0.f;
#pragma unroll
            for (int w = 0; w < 8; w++) { st += red0[w][tid]; sst += red1[w][tid]; }
            float mean = st * (1.f / 256.f);
            float var  = sst * (1.f / 256.f) - mean * mean;
            rowMean[tid] = mean;
            rowRstd[tid] = rsqrtf(var + 1e-5f);
        }
        __syncthreads();
#pragma unroll
        for (int nt = 0; nt < 2; nt++) {
            const int col = wave * 32 + nt * 16 + lx;
            const float gv = g2[l * 256 + col], bbv = b2[l * 256 + col];
#pragma unroll
            for (int mt = 0; mt < 4; mt++)
#pragma unroll
                for (int r = 0; r < 4; r++) {
                    int row = mt * 16 + quad * 4 + r;
                    float v = (z[mt][nt][r] - rowMean[row]) * rowRstd[row] * gv + bbv;
                    bufH[row * LDST + col] = (bf16)fmaxf(v, 0.f);
                }
        }
    }
    __syncthreads();

    // ================= reg layer 2: relu(y1@rw2+rb2) -> bufA =================
    gemm64(bufB, rw2t + (size_t)l * 65536, wave, lane, acc);
    {
#pragma unroll
        for (int nt = 0; nt < 2; nt++) {
            const int col = wave * 32 + nt * 16 + lx;
            const float bv = rb2[l * 256 + col];
#pragma unroll
            for (int mt = 0; mt < 4; mt++)
#pragma unroll
                for (int r = 0; r < 4; r++) {
                    int row = mt * 16 + quad * 4 + r;
                    bufA[row * LDST + col] = (bf16)fmaxf(acc[mt][nt][r] + bv, 0.f);
                }
        }
    }
    __syncthreads();

    // ================= final layers: waves 0-3 cls out, waves 4-7 coord out =================
    if (wave < 4) {
        // cls = x2 @ cw3 + cb3 -> out[0][l][row][0..9]
        f32x4 c = gemm16(bufH, cw3t + (size_t)l * 4096, wave * 16, lane);
        if (lx < 10) {
            const float bv = cb3[l * 10 + lx];
#pragma unroll
            for (int r = 0; r < 4; r++) {
                int row = row0 + wave * 16 + quad * 4 + r;
                out[((size_t)l * 28800 + row) * 10 + lx] = c[r] + bv;
            }
        }
    } else {
        // tmp = y2 @ rw3 + rb3 -> coord transform -> out[1][l][row][0..9]
        const int w2 = wave - 4;
        f32x4 t = gemm16(bufA, rw3t + (size_t)l * 4096, w2 * 16, lane);
        if (lx < 10) {
            const float bv = rb3[l * 10 + lx];
            const float* refp = (l == 0) ? init_ref : (inter_ref + (size_t)(l - 1) * 28800 * 3);
#pragma unroll
            for (int r = 0; r < 4; r++) {
                int row = row0 + w2 * 16 + quad * 4 + r;
                float v = t[r] + bv;
                float o;
                if (lx == 0 || lx == 1 || lx == 4) {
                    int rc = (lx == 4) ? 2 : lx;
                    float x = refp[(size_t)row * 3 + rc];
                    x = fminf(fmaxf(x, 0.f), 1.f);
                    float x1 = fmaxf(x, 1e-5f);
                    float x2 = fmaxf(1.f - x, 1e-5f);
                    float ris = logf(x1) - logf(x2);
                    float sg = 1.f / (1.f + expf(-(v + ris)));
                    o = (lx == 4) ? (sg * 8.f - 5.f) : (sg * 102.4f - 51.2f);
                } else {
                    o = v;
                }
                out[(size_t)(6 + l) * 28800 * 10 + (size_t)row * 10 + lx] = o;
            }
        }
    }
}

extern "C" void kernel_launch(void* const* d_in, const int* in_sizes, int n_in,
                              void* d_out, int out_size, void* d_ws, size_t ws_size,
                              hipStream_t stream)
{
    const float* hs        = (const float*)d_in[0];
    const float* init_ref  = (const float*)d_in[1];
    const float* inter_ref = (const float*)d_in[2];
    const float* cls_w1    = (const float*)d_in[3];
    const float* cls_b1    = (const float*)d_in[4];
    const float* ln1_g     = (const float*)d_in[5];
    const float* ln1_b     = (const float*)d_in[6];
    const float* cls_w2    = (const float*)d_in[7];
    const float* cls_b2    = (const float*)d_in[8];
    const float* ln2_g     = (const float*)d_in[9];
    const float* ln2_b     = (const float*)d_in[10];
    const float* cls_w3    = (const float*)d_in[11];
    const float* cls_b3    = (const float*)d_in[12];
    const float* reg_w1    = (const float*)d_in[13];
    const float* reg_b1    = (const float*)d_in[14];
    const float* reg_w2    = (const float*)d_in[15];
    const float* reg_b2    = (const float*)d_in[16];
    const float* reg_w3    = (const float*)d_in[17];
    const float* reg_b3    = (const float*)d_in[18];

    bf16* ws   = (bf16*)d_ws;
    bf16* cw1t = ws;                  // 6*65536
    bf16* cw2t = cw1t + 393216;
    bf16* rw1t = cw2t + 393216;
    bf16* rw2t = rw1t + 393216;
    bf16* cw3t = rw2t + 393216;       // 6*16*256
    bf16* rw3t = cw3t + 24576;

    transpose_weights<<<dim3(4, 4, 6), 256, 0, stream>>>(cls_w1, cw1t);
    transpose_weights<<<dim3(4, 4, 6), 256, 0, stream>>>(cls_w2, cw2t);
    transpose_weights<<<dim3(4, 4, 6), 256, 0, stream>>>(reg_w1, rw1t);
    transpose_weights<<<dim3(4, 4, 6), 256, 0, stream>>>(reg_w2, rw2t);
    prep_small<<<96, 256, 0, stream>>>(cls_w3, cw3t);
    prep_small<<<96, 256, 0, stream>>>(reg_w3, rw3t);

    head_kernel<<<dim3(450, 6), 512, 0, stream>>>(
        hs, init_ref, inter_ref,
        cw1t, cw2t, rw1t, rw2t, cw3t, rw3t,
        cls_b1, ln1_g, ln1_b, cls_b2, ln2_g, ln2_b, cls_b3,
        reg_b1, reg_b2, reg_b3, (float*)d_out);
}

// Round 2
// 522.081 us; speedup vs baseline: 1.2160x; 1.2160x over previous
//
#include <hip/hip_runtime.h>
#include <hip/hip_bf16.h>

typedef __bf16 bf16;
typedef __bf16 bf16x8 __attribute__((ext_vector_type(8)));
typedef float f32x4 __attribute__((ext_vector_type(4)));

#define ROWS 64
#define LDST 264  // 256 + 8 pad: row stride 528 B (16B-aligned, 4-bank shift/row)

// ---------------- prep: transpose all four [6][256][256] fp32 weight sets -> bf16 [N][K] ----------------
__global__ void transpose_all(const float* __restrict__ w0, const float* __restrict__ w1,
                              const float* __restrict__ w2, const float* __restrict__ w3,
                              bf16* __restrict__ out)
{
    __shared__ float tile[64][65];
    const int mz  = blockIdx.z;             // 0..23 = mat*6 + level
    const int mat = mz / 6;
    const float* srcs[4] = {w0, w1, w2, w3};
    const float* src = srcs[mat] + (size_t)(mz % 6) * 65536;
    bf16* dst = out + (size_t)mz * 65536;
    const int k0 = blockIdx.x * 64;
    const int n0 = blockIdx.y * 64;
    const int tx = threadIdx.x & 63, ty = threadIdx.x >> 6;
#pragma unroll
    for (int i = ty; i < 64; i += 4)
        tile[i][tx] = src[(size_t)(k0 + i) * 256 + n0 + tx];
    __syncthreads();
#pragma unroll
    for (int i = ty; i < 64; i += 4)
        dst[(size_t)(n0 + i) * 256 + k0 + tx] = (bf16)tile[tx][i];
}

// ---------------- prep: [6][256][10] -> [6][16][256] bf16, transposed + zero-padded (both w3s) ----------------
__global__ void prep_small(const float* __restrict__ cw3, const float* __restrict__ rw3,
                           bf16* __restrict__ outc, bf16* __restrict__ outr)
{
    int idx = blockIdx.x * 256 + threadIdx.x;  // 0..49151
    const float* w = (idx < 24576) ? cw3 : rw3;
    bf16* o = (idx < 24576) ? outc : outr;
    int j = (idx < 24576) ? idx : idx - 24576;
    int k = j & 255;
    int n = (j >> 8) & 15;
    int l = j >> 12;
    float v = (n < 10) ? w[((size_t)l * 256 + k) * 10 + n] : 0.0f;
    o[j] = (bf16)v;
}

// ---------------- main fused head kernel ----------------
__device__ __forceinline__ unsigned int pack2(float lo, float hi)
{
    union { bf16 h[2]; unsigned int u; } p;
    p.h[0] = (bf16)lo; p.h[1] = (bf16)hi;
    return p.u;
}

// 64x256 tile GEMM: acc[4 m-tiles][2 n-tiles], wave owns cols [wave*32, wave*32+32)
__device__ __forceinline__ void gemm64(const bf16* __restrict__ bufIn,
                                       const bf16* __restrict__ wt,
                                       int wave, int lane, f32x4 acc[4][2])
{
    const int quad = lane >> 4, lx = lane & 15;
    const int ncol0 = wave * 32;
#pragma unroll
    for (int mt = 0; mt < 4; mt++)
#pragma unroll
        for (int nt = 0; nt < 2; nt++)
            acc[mt][nt] = f32x4{0.f, 0.f, 0.f, 0.f};
#pragma unroll
    for (int kk = 0; kk < 8; kk++) {
        const int k0 = kk * 32 + quad * 8;
        bf16x8 a[4], b[2];
#pragma unroll
        for (int mt = 0; mt < 4; mt++)
            a[mt] = *(const bf16x8*)&bufIn[(mt * 16 + lx) * LDST + k0];
#pragma unroll
        for (int nt = 0; nt < 2; nt++)
            b[nt] = *(const bf16x8*)&wt[(ncol0 + nt * 16 + lx) * 256 + k0];
#pragma unroll
        for (int mt = 0; mt < 4; mt++)
#pragma unroll
            for (int nt = 0; nt < 2; nt++)
                acc[mt][nt] = __builtin_amdgcn_mfma_f32_16x16x32_bf16(a[mt], b[nt], acc[mt][nt], 0, 0, 0);
    }
}

// 16x256 @ 256x16 GEMM (final small layers)
__device__ __forceinline__ f32x4 gemm16(const bf16* __restrict__ bufIn,
                                        const bf16* __restrict__ wt,
                                        int mrow0, int lane)
{
    const int quad = lane >> 4, lx = lane & 15;
    f32x4 acc = f32x4{0.f, 0.f, 0.f, 0.f};
#pragma unroll
    for (int kk = 0; kk < 8; kk++) {
        const int k0 = kk * 32 + quad * 8;
        bf16x8 a = *(const bf16x8*)&bufIn[(mrow0 + lx) * LDST + k0];
        bf16x8 b = *(const bf16x8*)&wt[lx * 256 + k0];
        acc = __builtin_amdgcn_mfma_f32_16x16x32_bf16(a, b, acc, 0, 0, 0);
    }
    return acc;
}

// packed store: even lanes write col pair (lx, lx+1) of nt0, odd lanes pair (16+lx-1, 16+lx) of nt1
__device__ __forceinline__ void store_packed(bf16* __restrict__ dst, int wave, int lane,
                                             const float v[4][2][4])
{
    const int quad = lane >> 4, lx = lane & 15;
    const bool even = (lx & 1) == 0;
    const int col = even ? (wave * 32 + lx) : (wave * 32 + 16 + lx - 1);
#pragma unroll
    for (int mt = 0; mt < 4; mt++)
#pragma unroll
        for (int r = 0; r < 4; r++) {
            float my0 = v[mt][0][r], my1 = v[mt][1][r];
            float p0 = __shfl_xor(my0, 1);
            float p1 = __shfl_xor(my1, 1);
            float lo = even ? my0 : p1;
            float hi = even ? p0  : my1;
            int row = mt * 16 + quad * 4 + r;
            *(unsigned int*)&dst[row * LDST + col] = pack2(lo, hi);
        }
}

// LN epilogue: acc+bias -> stats (shfl + cross-wave LDS) -> LN*g+b, relu -> v
__device__ __forceinline__ void ln_epilogue(const f32x4 acc[4][2], float v[4][2][4],
                                            const float* __restrict__ bias,
                                            const float* __restrict__ g,
                                            const float* __restrict__ b,
                                            float (*red0)[ROWS], float (*red1)[ROWS],
                                            float* rowMean, float* rowRstd,
                                            int wave, int lane, int tid)
{
    const int quad = lane >> 4, lx = lane & 15;
    const float bv0 = bias[wave * 32 + lx];
    const float bv1 = bias[wave * 32 + 16 + lx];
    float s[16], ss[16];
#pragma unroll
    for (int mt = 0; mt < 4; mt++)
#pragma unroll
        for (int r = 0; r < 4; r++) {
            float a0 = acc[mt][0][r] + bv0;
            float a1 = acc[mt][1][r] + bv1;
            v[mt][0][r] = a0; v[mt][1][r] = a1;
            s[mt * 4 + r]  = a0 + a1;
            ss[mt * 4 + r] = a0 * a0 + a1 * a1;
        }
#pragma unroll
    for (int off = 1; off < 16; off <<= 1)
#pragma unroll
        for (int i = 0; i < 16; i++) {
            s[i]  += __shfl_xor(s[i], off);
            ss[i] += __shfl_xor(ss[i], off);
        }
    if (lx == 0) {
#pragma unroll
        for (int mt = 0; mt < 4; mt++)
#pragma unroll
            for (int r = 0; r < 4; r++) {
                int row = mt * 16 + quad * 4 + r;
                red0[wave][row] = s[mt * 4 + r];
                red1[wave][row] = ss[mt * 4 + r];
            }
    }
    __syncthreads();   // also guarantees all gemm LDS reads retired -> in-place store safe after this
    if (tid < ROWS) {
        float st = 0.f, sst = 0.f;
#pragma unroll
        for (int w = 0; w < 8; w++) { st += red0[w][tid]; sst += red1[w][tid]; }
        float mean = st * (1.f / 256.f);
        float var  = sst * (1.f / 256.f) - mean * mean;
        rowMean[tid] = mean;
        rowRstd[tid] = rsqrtf(var + 1e-5f);
    }
    __syncthreads();
    const float g0 = g[wave * 32 + lx],      b0 = b[wave * 32 + lx];
    const float g1v = g[wave * 32 + 16 + lx], b1v = b[wave * 32 + 16 + lx];
#pragma unroll
    for (int mt = 0; mt < 4; mt++)
#pragma unroll
        for (int r = 0; r < 4; r++) {
            int row = mt * 16 + quad * 4 + r;
            float m = rowMean[row], rs = rowRstd[row];
            v[mt][0][r] = fmaxf((v[mt][0][r] - m) * rs * g0 + b0, 0.f);
            v[mt][1][r] = fmaxf((v[mt][1][r] - m) * rs * g1v + b1v, 0.f);
        }
}

__device__ __forceinline__ void bias_relu(const f32x4 acc[4][2], float v[4][2][4],
                                          const float* __restrict__ bias, int wave, int lane)
{
    const int lx = lane & 15;
    const float bv0 = bias[wave * 32 + lx];
    const float bv1 = bias[wave * 32 + 16 + lx];
#pragma unroll
    for (int mt = 0; mt < 4; mt++)
#pragma unroll
        for (int r = 0; r < 4; r++) {
            v[mt][0][r] = fmaxf(acc[mt][0][r] + bv0, 0.f);
            v[mt][1][r] = fmaxf(acc[mt][1][r] + bv1, 0.f);
        }
}

__global__ __launch_bounds__(512, 4) void head_kernel(
    const float* __restrict__ hs, const float* __restrict__ init_ref,
    const float* __restrict__ inter_ref,
    const bf16* __restrict__ cw1t, const bf16* __restrict__ cw2t,
    const bf16* __restrict__ rw1t, const bf16* __restrict__ rw2t,
    const bf16* __restrict__ cw3t, const bf16* __restrict__ rw3t,
    const float* __restrict__ cb1, const float* __restrict__ g1, const float* __restrict__ b1,
    const float* __restrict__ cb2, const float* __restrict__ g2, const float* __restrict__ b2,
    const float* __restrict__ cb3,
    const float* __restrict__ rb1, const float* __restrict__ rb2, const float* __restrict__ rb3,
    float* __restrict__ out)
{
    __shared__ bf16 bufH[ROWS * LDST];   // h, live for whole block
    __shared__ bf16 bufW[ROWS * LDST];   // recycled: x1 -> x2 -> y1 -> y2
    __shared__ float red0[8][ROWS];
    __shared__ float red1[8][ROWS];
    __shared__ float rowMean[ROWS];
    __shared__ float rowRstd[ROWS];

    const int l    = blockIdx.y;
    const int row0 = blockIdx.x * ROWS;
    const int tid  = threadIdx.x;
    const int wave = tid >> 6;
    const int lane = tid & 63;
    const int quad = lane >> 4;
    const int lx   = lane & 15;

    // ---- stage h tile: hs[l][q][b][:] -> bufH[r][:] bf16, r = b*900 + q ----
    for (int ri = wave; ri < ROWS; ri += 8) {
        const int r = row0 + ri;
        const int b = r / 900;
        const int q = r - b * 900;
        const float4* src = (const float4*)(hs + (((size_t)l * 900 + q) * 32 + b) * 256);
        float4 vv = src[lane];
        union { bf16 h[4]; uint2 u; } pk;
        pk.h[0] = (bf16)vv.x; pk.h[1] = (bf16)vv.y; pk.h[2] = (bf16)vv.z; pk.h[3] = (bf16)vv.w;
        *(uint2*)&bufH[ri * LDST + lane * 4] = pk.u;
    }
    __syncthreads();

    f32x4 acc[4][2];
    float v[4][2][4];

    // ===== cls1: LN(h@cw1+cb1), relu -> bufW =====
    gemm64(bufH, cw1t + (size_t)l * 65536, wave, lane, acc);
    ln_epilogue(acc, v, cb1 + l * 256, g1 + l * 256, b1 + l * 256,
                red0, red1, rowMean, rowRstd, wave, lane, tid);
    store_packed(bufW, wave, lane, v);
    __syncthreads();

    // ===== cls2: LN(x1@cw2+cb2), relu -> bufW (in place; ln_epilogue's sync covers the hazard) =====
    gemm64(bufW, cw2t + (size_t)l * 65536, wave, lane, acc);
    ln_epilogue(acc, v, cb2 + l * 256, g2 + l * 256, b2 + l * 256,
                red0, red1, rowMean, rowRstd, wave, lane, tid);
    store_packed(bufW, wave, lane, v);
    __syncthreads();

    // ===== cls3 (waves 0-3, reads bufW) overlapped with reg1 gemm (all waves, reads bufH) =====
    if (wave < 4) {
        f32x4 c = gemm16(bufW, cw3t + (size_t)l * 4096, wave * 16, lane);
        if (lx < 10) {
            const float bv = cb3[l * 10 + lx];
#pragma unroll
            for (int r = 0; r < 4; r++) {
                int row = row0 + wave * 16 + quad * 4 + r;
                out[((size_t)l * 28800 + row) * 10 + lx] = c[r] + bv;
            }
        }
    }
    gemm64(bufH, rw1t + (size_t)l * 65536, wave, lane, acc);
    __syncthreads();   // cls3's bufW reads + reg1's bufH reads all retired
    bias_relu(acc, v, rb1 + l * 256, wave, lane);
    store_packed(bufW, wave, lane, v);   // y1
    __syncthreads();

    // ===== reg2: relu(y1@rw2+rb2) -> bufW (in place) =====
    gemm64(bufW, rw2t + (size_t)l * 65536, wave, lane, acc);
    __syncthreads();   // all reads retired before in-place store
    bias_relu(acc, v, rb2 + l * 256, wave, lane);
    store_packed(bufW, wave, lane, v);   // y2
    __syncthreads();

    // ===== reg3 (waves 4-7): tmp = y2@rw3+rb3 -> coord transform -> out =====
    if (wave >= 4) {
        const int w2 = wave - 4;
        f32x4 t = gemm16(bufW, rw3t + (size_t)l * 4096, w2 * 16, lane);
        if (lx < 10) {
            const float bv = rb3[l * 10 + lx];
            const float* refp = (l == 0) ? init_ref : (inter_ref + (size_t)(l - 1) * 28800 * 3);
#pragma unroll
            for (int r = 0; r < 4; r++) {
                int row = row0 + w2 * 16 + quad * 4 + r;
                float vv = t[r] + bv;
                float o;
                if (lx == 0 || lx == 1 || lx == 4) {
                    int rc = (lx == 4) ? 2 : lx;
                    float x = refp[(size_t)row * 3 + rc];
                    x = fminf(fmaxf(x, 0.f), 1.f);
                    float x1 = fmaxf(x, 1e-5f);
                    float x2 = fmaxf(1.f - x, 1e-5f);
                    float ris = logf(x1) - logf(x2);
                    float sg = 1.f / (1.f + expf(-(vv + ris)));
                    o = (lx == 4) ? (sg * 8.f - 5.f) : (sg * 102.4f - 51.2f);
                } else {
                    o = vv;
                }
                out[(size_t)(6 + l) * 28800 * 10 + (size_t)row * 10 + lx] = o;
            }
        }
    }
}

extern "C" void kernel_launch(void* const* d_in, const int* in_sizes, int n_in,
                              void* d_out, int out_size, void* d_ws, size_t ws_size,
                              hipStream_t stream)
{
    const float* hs        = (const float*)d_in[0];
    const float* init_ref  = (const float*)d_in[1];
    const float* inter_ref = (const float*)d_in[2];
    const float* cls_w1    = (const float*)d_in[3];
    const float* cls_b1    = (const float*)d_in[4];
    const float* ln1_g     = (const float*)d_in[5];
    const float* ln1_b     = (const float*)d_in[6];
    const float* cls_w2    = (const float*)d_in[7];
    const float* cls_b2    = (const float*)d_in[8];
    const float* ln2_g     = (const float*)d_in[9];
    const float* ln2_b     = (const float*)d_in[10];
    const float* cls_w3    = (const float*)d_in[11];
    const float* cls_b3    = (const float*)d_in[12];
    const float* reg_w1    = (const float*)d_in[13];
    const float* reg_b1    = (const float*)d_in[14];
    const float* reg_w2    = (const float*)d_in[15];
    const float* reg_b2    = (const float*)d_in[16];
    const float* reg_w3    = (const float*)d_in[17];
    const float* reg_b3    = (const float*)d_in[18];

    bf16* ws   = (bf16*)d_ws;
    bf16* cw1t = ws;                  // [0] of 4 contiguous 6*65536 regions
    bf16* cw2t = cw1t + 393216;
    bf16* rw1t = cw2t + 393216;
    bf16* rw2t = rw1t + 393216;
    bf16* cw3t = rw2t + 393216;       // 6*16*256
    bf16* rw3t = cw3t + 24576;

    transpose_all<<<dim3(4, 4, 24), 256, 0, stream>>>(cls_w1, cls_w2, reg_w1, reg_w2, cw1t);
    prep_small<<<192, 256, 0, stream>>>(cls_w3, reg_w3, cw3t, rw3t);

    head_kernel<<<dim3(450, 6), 512, 0, stream>>>(
        hs, init_ref, inter_ref,
        cw1t, cw2t, rw1t, rw2t, cw3t, rw3t,
        cls_b1, ln1_g, ln1_b, cls_b2, ln2_g, ln2_b, cls_b3,
        reg_b1, reg_b2, reg_b3, (float*)d_out);
}